// Round 8
// baseline (361.386 us; speedup 1.0000x reference)
//
#include <hip/hip_runtime.h>

#define BB 64
#define CC 64
#define TT 4000

#define NSLAB 8              // slabs (apply ranges) per batch; grid = 64*8 = 512
#define NCHUNK 16
#define TCH 250              // t per chunk; staged padded to 256 (32 x 8-short chunks)
#define GP_PITCH 264         // shorts per LDS row (16B-aligned rows, chunk 32 = pad)
#define APITCH 72            // shorts per al row

typedef short short8 __attribute__((ext_vector_type(8)));
typedef float f32x16 __attribute__((ext_vector_type(16)));

__device__ __forceinline__ short f2bf(float f) {
    unsigned u = __float_as_uint(f);
    u = (u + 0x7FFFu + ((u >> 16) & 1u)) >> 16;   // round-to-nearest-even
    return (short)u;
}
// packed RNE f32x2 -> bf16x2 (lo = a, hi = b)
__device__ __forceinline__ unsigned cvt_pk(float a, float b) {
    unsigned r;
    asm("v_cvt_pk_bf16_f32 %0, %1, %2" : "=v"(r) : "v"(a), "v"(b));
    return r;
}
__device__ __forceinline__ float bfpair(unsigned u) {   // sum of 2 packed bf16
    return __uint_as_float(u << 16) + __uint_as_float(u & 0xFFFF0000u);
}
__device__ __forceinline__ float bf2f(short s) {
    return __uint_as_float(((unsigned)(unsigned short)s) << 16);
}

// ---- staging helpers (verbatim from the verified R5 kernel) ----
__device__ __forceinline__ void stage_load(const float* __restrict__ xb, int t0,
                                           int g, int tid, float4 v[8]) {
    #pragma unroll
    for (int k = 0; k < 8; ++k) {
        const int i = tid + 256 * (g * 8 + k);
        const int row = i >> 6, tq = i & 63;               // t_local = 4*tq
        float4 w = make_float4(0.f, 0.f, 0.f, 0.f);
        if (tq < 62) {
            w = *(const float4*)(xb + row * TT + t0 + 4 * tq);
        } else if (tq == 62) {
            const float* p = xb + row * TT + t0 + 248;
            w.x = p[0]; w.y = p[1];
        }
        v[k] = w;
    }
}
__device__ __forceinline__ void stage_write(short* xs, int g, int tid, const float4 v[8]) {
    #pragma unroll
    for (int k = 0; k < 8; ++k) {
        const int i = tid + 256 * (g * 8 + k);
        const int row = i >> 6, tq = i & 63;
        uint2 sv;
        sv.x = cvt_pk(v[k].x, v[k].y);
        sv.y = cvt_pk(v[k].z, v[k].w);
        const int pc = (tq >> 1) ^ (row & 7);              // swizzled chunk
        *(uint2*)(xs + row * GP_PITCH + pc * 8 + (tq & 1) * 4) = sv;
    }
}
__device__ __forceinline__ float s_partial(const short* xs, int lane, int wave) {
    const short* rowp = xs + lane * GP_PITCH;
    float s = 0.f;
    #pragma unroll
    for (int j = 0; j < 8; ++j) {
        const int pc = (wave * 8 + j) ^ (lane & 7);
        uint2 u0 = *(const uint2*)(rowp + pc * 8);
        uint2 u1 = *(const uint2*)(rowp + pc * 8 + 4);
        s += bfpair(u0.x) + bfpair(u0.y) + bfpair(u1.x) + bfpair(u1.y);
    }
    return s;
}
__device__ __forceinline__ void mfma_tile(const short* xs, int r0, int c0,
                                          int m, int half, f32x16& acc) {
    #pragma unroll
    for (int ks = 0; ks < 16; ++ks) {
        const int ck = ks * 2 + half;                      // logical 8-short chunk of k
        short8 av = *(const short8*)(xs + (r0 + m) * GP_PITCH + (ck ^ (m & 7)) * 8);
        short8 bv = *(const short8*)(xs + (c0 + m) * GP_PITCH + (ck ^ (m & 7)) * 8);
        acc = __builtin_amdgcn_mfma_f32_32x32x16_bf16(av, bv, acc, 0, 0, 0);
    }
}

// ONE kernel, 512 blocks = (slab, b); b = blockIdx&63 so all 8 slabs of a batch
// share an XCD and stream chunks in the SAME order -> 7/8 of x reads are L2 hits.
// Each block computes its batch's FULL gram itself (K-accumulated over 16 chunks)
// -> no G_part round-trip, no second kernel, no grid sync, no workspace.
// Then in-block softmax (acc -> Es dump), then 2 x 250-t apply rounds whose
// B-frags + bf16 residual come straight from the gram-swizzled LDS buffer.
__global__ __launch_bounds__(256)
void fused_ca(const float* __restrict__ x,
              const float* __restrict__ w1, const float* __restrict__ b1,
              const float* __restrict__ w2, const float* __restrict__ b2,
              const float* __restrict__ gamma, float* __restrict__ out) {
    __shared__ short buf[CC * GP_PITCH];   // 33.8 KB: one 250-t chunk, gram-swizzled
    __shared__ float Es[64 * 65];          // 16.6 KB: full gram of batch b
    __shared__ short al[CC * APITCH];      // 9.2 KB:  al[e][c] = bf16(P[c][e])
    __shared__ float red[3 * 256];         // 3 KB
    __shared__ float Sb[64];               // total 61.9 KB -> 2 blocks/CU

    const int tid  = threadIdx.x;
    const int lane = tid & 63, wave = tid >> 6;
    const int b    = blockIdx.x & 63;
    const int slab = blockIdx.x >> 6;
    const float* xb = x + (size_t)b * CC * TT;
    const int m = lane & 31, half = lane >> 5;
    const int r0 = (wave >> 1) * 32, c0w = (wave & 1) * 32;

    // ================= phase 1: full gram for batch b =================
    f32x16 acc;
    #pragma unroll
    for (int z = 0; z < 16; ++z) acc[z] = 0.f;
    float s_acc = 0.f;

    float4 v0[8], v1[8];
    stage_load(xb, 0, 0, tid, v0);
    stage_load(xb, 0, 1, tid, v1);
    for (int ch = 0; ch < NCHUNK; ++ch) {
        stage_write(buf, 0, tid, v0);
        stage_write(buf, 1, tid, v1);
        __syncthreads();
        if (ch < NCHUNK - 1) {                 // prefetch next chunk (T14)
            stage_load(xb, (ch + 1) * TCH, 0, tid, v0);
            stage_load(xb, (ch + 1) * TCH, 1, tid, v1);
        }
        s_acc += s_partial(buf, lane, wave);
        mfma_tile(buf, r0, c0w, m, half, acc);  // K-accumulates across all chunks
        __syncthreads();                        // buf free for next chunk
    }

    // prefetch apply round-1 chunk (own slab, first half); consumed after softmax
    stage_load(xb, (2 * slab) * TCH, 0, tid, v0);
    stage_load(xb, (2 * slab) * TCH, 1, tid, v1);

    // S reduce + G dump to Es (same mapping as the old G_part global write)
    red[wave * 64 + lane] = s_acc;
    #pragma unroll
    for (int r = 0; r < 16; ++r) {
        const int row = (r & 3) + 8 * (r >> 2) + 4 * half;
        Es[(r0 + row) * 65 + (c0w + m)] = acc[r];
    }
    __syncthreads();
    if (tid < 64)
        Sb[tid] = red[tid] + red[64 + tid] + red[128 + tid] + red[192 + tid];

    // ================= phase 2: softmax (verbatim structure) =================
    {
        float A = 0.f, Bc = 0.f, Be = 0.f, Cc = 0.f;
        #pragma unroll
        for (int j = 0; j < 8; ++j) {
            float a1 = w1[j], a2 = w2[j], q1 = b1[j], q2 = b2[j];
            A += a1 * a2; Bc += a1 * q2; Be += q1 * a2; Cc += q1 * q2;
        }
        Cc *= (float)TT;
        __syncthreads();                      // Sb (and Es) visible to all

        const int c = lane, q = wave;
        const float sc = Sb[c];
        float ev[16], mn = 1e30f, mx = -1e30f;
        #pragma unroll
        for (int i = 0; i < 16; ++i) {
            const int e = 16 * q + i;
            float en = A * Es[c * 65 + e] + Bc * sc + Be * Sb[e] + Cc;
            ev[i] = en;
            mn = fminf(mn, en); mx = fmaxf(mx, en);
        }
        red[q * 64 + c] = mn; red[256 + q * 64 + c] = mx;
        __syncthreads();
        mn = fminf(fminf(red[c], red[64 + c]), fminf(red[128 + c], red[192 + c]));
        mx = fmaxf(fmaxf(red[256 + c], red[320 + c]), fmaxf(red[384 + c], red[448 + c]));
        const float ninv = 1.f / (mx - mn + 1e-8f);
        float pv[16], ls = 0.f;
        #pragma unroll
        for (int i = 0; i < 16; ++i) {
            float p = __expf((ev[i] - mn) * ninv);
            pv[i] = p; ls += p;
        }
        red[512 + q * 64 + c] = ls;
        __syncthreads();
        const float rinv = 1.f / (red[512 + c] + red[576 + c] + red[640 + c] + red[704 + c]);
        // al[e][c] = bf16(attention[c][e])
        #pragma unroll
        for (int i = 0; i < 16; ++i)
            al[(16 * q + i) * APITCH + c] = f2bf(pv[i] * rinv);
    }
    __syncthreads();                          // al ready; Es dead; buf dead

    // ================= phase 3: apply, 2 rounds of 250 t =================
    {
        const float gm = gamma[0];
        float* ob = out + (size_t)b * CC * TT;
        const int tb = (wave >> 1) * 64;
        short8 av[4];
        #pragma unroll
        for (int ks = 0; ks < 4; ++ks)
            av[ks] = *(const short8*)(al + (c0w + m) * APITCH + ks * 16 + 8 * half);

        for (int hr = 0; hr < 2; ++hr) {
            stage_write(buf, 0, tid, v0);     // own-slab chunk (prefetched)
            stage_write(buf, 1, tid, v1);
            __syncthreads();
            if (hr == 0) {                    // prefetch round-2 chunk under round-1
                stage_load(xb, (2 * slab + 1) * TCH, 0, tid, v0);
                stage_load(xb, (2 * slab + 1) * TCH, 1, tid, v1);
            }
            const int tg0 = (2 * slab + hr) * TCH;   // global t base of this round

            #pragma unroll
            for (int it = 0; it < 2; ++it) {
                const int tl0 = it * 128 + tb + m;   // 0..255 (pad cols guarded below)
                const int tl1 = tl0 + 32;
                const int tq0 = tl0 >> 3, tq1 = tl1 >> 3, el = tl0 & 7;
                f32x16 acc0, acc1;
                #pragma unroll
                for (int z = 0; z < 16; ++z) { acc0[z] = 0.f; acc1[z] = 0.f; }

                #pragma unroll
                for (int ks = 0; ks < 4; ++ks) {
                    short8 bv0, bv1;
                    #pragma unroll
                    for (int j = 0; j < 8; ++j) {
                        const int e = ks * 16 + 8 * half + j;
                        const short* rp = buf + e * GP_PITCH;
                        bv0[j] = rp[((tq0 ^ (e & 7)) << 3) + el];
                        bv1[j] = rp[((tq1 ^ (e & 7)) << 3) + el];
                    }
                    acc0 = __builtin_amdgcn_mfma_f32_32x32x16_bf16(av[ks], bv0, acc0, 0, 0, 0);
                    acc1 = __builtin_amdgcn_mfma_f32_32x32x16_bf16(av[ks], bv1, acc1, 0, 0, 0);
                }

                #pragma unroll
                for (int r = 0; r < 16; ++r) {
                    const int row = (r & 3) + 8 * (r >> 2) + 4 * half;
                    const int cch = c0w + row;
                    const short* rp = buf + cch * GP_PITCH;
                    if (tl0 < TCH)
                        ob[cch * TT + tg0 + tl0] =
                            gm * acc0[r] + bf2f(rp[((tq0 ^ (cch & 7)) << 3) + el]);
                    if (tl1 < TCH)
                        ob[cch * TT + tg0 + tl1] =
                            gm * acc1[r] + bf2f(rp[((tq1 ^ (cch & 7)) << 3) + el]);
                }
            }
            if (hr == 0) __syncthreads();     // round-1 reads done before overwrite
        }
    }
}

extern "C" void kernel_launch(void* const* d_in, const int* in_sizes, int n_in,
                              void* d_out, int out_size, void* d_ws, size_t ws_size,
                              hipStream_t stream) {
    const float* x  = (const float*)d_in[0];
    const float* w1 = (const float*)d_in[1];
    const float* b1 = (const float*)d_in[2];
    const float* w2 = (const float*)d_in[3];
    const float* b2 = (const float*)d_in[4];
    const float* gm = (const float*)d_in[5];
    float* out = (float*)d_out;

    hipLaunchKernelGGL(fused_ca, dim3(BB * NSLAB), dim3(256), 0, stream,
                       x, w1, b1, w2, b2, gm, out);
}